// Round 4
// baseline (126.318 us; speedup 1.0000x reference)
//
#include <hip/hip_runtime.h>
#include <math.h>

#define N_IN  96
#define N_OUT 192
#define BW    24    // truncated band window width
#define SP    100   // padded LDS row stride (floats): 100%32=4 -> bank spread

__device__ __forceinline__ int fold_dct2(int idx, int n) {
    int p = 2 * n;
    int m = ((idx % p) + p) % p;
    return (m >= n) ? (p - 1 - m) : m;
}

__device__ __forceinline__ void fma4(float4& a, float w, const float4& v) {
    a.x += w * v.x; a.y += w * v.y; a.z += w * v.z; a.w += w * v.w;
}

// One-shot setup: per-thread analytic B row (4 taps) -> Thomas solve of
// A m_j = B_j (A tridiag, diag 2/3 except 5/6 at ends, off-diag 1/6) ->
// banded weight extraction.
//   WB8T [24 oct][24 t][8 jj] f32 : oct-aligned windows (start S8[oct])
//   WT4  [24 t][192 j]       f32 : quad-aligned 16B windows (start S4[j/4])
__global__ void setup_kernel(float* __restrict__ WB8T, float* __restrict__ WT4,
                             int* __restrict__ S8, int* __restrict__ S4) {
    __shared__ double cp[N_IN];
    __shared__ double minv[N_IN];
    __shared__ float  DP[N_IN][N_OUT];  // 73.7 KB
    int j = threadIdx.x;  // 0..191

    // B row j: taps at fold(b-1+k), weights w[k]
    double x  = (double)j * 95.0 / 191.0;
    double bf = floor(x);
    int    b  = (int)bf;
    double t  = x - bf;
    double t2 = t * t, t3 = t2 * t;
    double w[4] = {(1.0 - t) * (1.0 - t) * (1.0 - t) / 6.0,
                   (3.0 * t3 - 6.0 * t2 + 4.0) / 6.0,
                   (-3.0 * t3 + 3.0 * t2 + 3.0 * t + 1.0) / 6.0,
                   t3 / 6.0};
    int c[4];
    for (int k = 0; k < 4; ++k) c[k] = fold_dct2(b - 1 + k, N_IN);

    if (j == 0) {
        const double a = 1.0 / 6.0;
        minv[0] = 1.0 / (5.0 / 6.0);
        cp[0]   = a * minv[0];
        for (int i = 1; i < N_IN; ++i) {
            double bi  = (i == N_IN - 1) ? (5.0 / 6.0) : (2.0 / 3.0);
            double den = bi - a * cp[i - 1];
            minv[i] = 1.0 / den;
            cp[i]   = a * minv[i];
        }
    }
    __syncthreads();

    const double a = 1.0 / 6.0;
    double dp = 0.0;
    for (int i = 0; i < N_IN; ++i) {
        double Bji = 0.0;
        for (int k = 0; k < 4; ++k) if (c[k] == i) Bji += w[k];
        dp = (i == 0) ? Bji * minv[0] : (Bji - a * dp) * minv[i];
        DP[i][j] = (float)dp;
    }

    int j8 = j & ~7;
    int b8 = (j8 * 95) / 191;
    int s8 = b8 - 9; s8 = s8 < 0 ? 0 : (s8 > 72 ? 72 : s8);
    int j4 = j & ~3;
    int b4 = (j4 * 95) / 191;
    int s4 = b4 - 9; s4 = s4 < 0 ? 0 : (s4 > 72 ? 72 : s4);
    s4 &= ~3;
    if ((j & 7) == 0) S8[j >> 3] = s8;
    if ((j & 3) == 0) S4[j >> 2] = s4;

    double xv = 0.0;
    for (int i = N_IN - 1; i >= 0; --i) {
        xv = (i == N_IN - 1) ? (double)DP[i][j] : ((double)DP[i][j] - cp[i] * xv);
        float m  = (float)xv;
        int  t8 = i - s8;
        if (t8 >= 0 && t8 < BW) WB8T[((j >> 3) * BW + t8) * 8 + (j & 7)] = m;
        int  t4 = i - s4;
        if (t4 >= 0 && t4 < BW) WT4[t4 * N_OUT + j] = m;
    }
}

// Pass 1: expand x. in [4][96][QUADS*4] -> out [4][192][QUADS*4].
// blockIdx.y = output oct; weights are wave-uniform (s_load float4 pairs).
template <int QUADS>
__global__ __launch_bounds__(256)
void pass_x_kernel(const float4* __restrict__ in, float4* __restrict__ out,
                   const float* __restrict__ WB8T, const int* __restrict__ S8) {
    int g  = blockIdx.x * 256 + threadIdx.x;
    int o  = g / QUADS;
    int q  = g - o * QUADS;
    int jo = blockIdx.y;
    int S  = S8[jo];
    const float4* ip = in + ((size_t)o * N_IN + S) * QUADS + q;
    const float4* wp = (const float4*)(WB8T + jo * BW * 8);
    float4 acc[8];
#pragma unroll
    for (int jj = 0; jj < 8; ++jj) acc[jj] = make_float4(0.f, 0.f, 0.f, 0.f);
#pragma unroll
    for (int t = 0; t < BW; ++t) {
        float4 v   = ip[(size_t)t * QUADS];
        float4 wlo = wp[2 * t];
        float4 whi = wp[2 * t + 1];
        fma4(acc[0], wlo.x, v); fma4(acc[1], wlo.y, v);
        fma4(acc[2], wlo.z, v); fma4(acc[3], wlo.w, v);
        fma4(acc[4], whi.x, v); fma4(acc[5], whi.y, v);
        fma4(acc[6], whi.z, v); fma4(acc[7], whi.w, v);
    }
    float4* op = out + ((size_t)o * N_OUT + jo * 8) * QUADS + q;
#pragma unroll
    for (int jj = 0; jj < 8; ++jj) op[(size_t)jj * QUADS] = acc[jj];
}

// Fused pass 2+3: per (bc,x') slice, [96 y][96 z] -> [192 y'][192 z'].
// Stage 0: slab -> LDS. Stage A (per 96-row half): y-expand into Ty LDS.
// Stage B: z-expand from Ty, coalesced float4 stores to global.
__global__ __launch_bounds__(384)
void pass_yz_kernel(const float* __restrict__ T1, float* __restrict__ out,
                    const float* __restrict__ WB8T, const float* __restrict__ WT4,
                    const int* __restrict__ S8, const int* __restrict__ S4) {
    __shared__ float S_lds[N_IN * SP];  // 38.4 KB
    __shared__ float Ty[N_IN * SP];     // 38.4 KB
    int o   = blockIdx.x;   // 0..767  (bc*192 + x')
    int tid = threadIdx.x;  // 0..383

    // Stage 0: load slab (2304 float4s, coalesced)
    const float4* ip = (const float4*)(T1 + (size_t)o * N_IN * N_IN);
    for (int f = tid; f < N_IN * N_IN / 4; f += 384) {
        int row = f / (N_IN / 4);
        int qc  = f - row * (N_IN / 4);
        *(float4*)(S_lds + row * SP + qc * 4) = ip[f];
    }

    // Stage-B weights: thread owns one z'-quad across 8 y-groups
    int zq  = tid % 48;       // z' quad
    int yg  = tid / 48;       // 0..7
    int S4z = S4[zq];
    float4 w[BW];
#pragma unroll
    for (int t = 0; t < BW; ++t)
        w[t] = *(const float4*)(WT4 + t * N_OUT + zq * 4);

    __syncthreads();

    for (int h = 0; h < 2; ++h) {
        // Stage A: 288 tasks (12 octs x 24 z-quads), threads 288..383 idle
        if (tid < 288) {
            int jo  = tid / 24;        // oct within half
            int q   = tid - jo * 24;   // z quad
            int joG = h * 12 + jo;
            int Sg  = S8[joG];
            const float4* wp = (const float4*)(WB8T + joG * BW * 8);
            float4 acc[8];
#pragma unroll
            for (int jj = 0; jj < 8; ++jj) acc[jj] = make_float4(0.f, 0.f, 0.f, 0.f);
#pragma unroll
            for (int t = 0; t < BW; ++t) {
                float4 v   = *(const float4*)(S_lds + (Sg + t) * SP + q * 4);
                float4 wlo = wp[2 * t];
                float4 whi = wp[2 * t + 1];
                fma4(acc[0], wlo.x, v); fma4(acc[1], wlo.y, v);
                fma4(acc[2], wlo.z, v); fma4(acc[3], wlo.w, v);
                fma4(acc[4], whi.x, v); fma4(acc[5], whi.y, v);
                fma4(acc[6], whi.z, v); fma4(acc[7], whi.w, v);
            }
#pragma unroll
            for (int jj = 0; jj < 8; ++jj)
                *(float4*)(Ty + (jo * 8 + jj) * SP + q * 4) = acc[jj];
        }
        __syncthreads();

        // Stage B: each thread: 12 y' rows x one z' quad
        float* ob = out + ((size_t)o * N_OUT + h * N_IN) * N_OUT;
#pragma unroll
        for (int rr = 0; rr < 12; ++rr) {
            int yl = yg * 12 + rr;
            const float4* tp = (const float4*)(Ty + yl * SP + S4z);
            float4 v0 = tp[0], v1 = tp[1], v2 = tp[2];
            float4 v3 = tp[3], v4 = tp[4], v5 = tp[5];
            float rv[BW] = {v0.x, v0.y, v0.z, v0.w, v1.x, v1.y, v1.z, v1.w,
                            v2.x, v2.y, v2.z, v2.w, v3.x, v3.y, v3.z, v3.w,
                            v4.x, v4.y, v4.z, v4.w, v5.x, v5.y, v5.z, v5.w};
            float4 acc = make_float4(0.f, 0.f, 0.f, 0.f);
#pragma unroll
            for (int t = 0; t < BW; ++t) fma4(acc, rv[t], w[t]);
            *(float4*)(ob + (size_t)yl * N_OUT + zq * 4) = acc;
        }
        __syncthreads();  // protect Ty before next half overwrites
    }
}

extern "C" void kernel_launch(void* const* d_in, const int* in_sizes, int n_in,
                              void* d_out, int out_size, void* d_ws, size_t ws_size,
                              hipStream_t stream) {
    const float* in  = (const float*)d_in[0];
    float*       out = (float*)d_out;
    char*        ws  = (char*)d_ws;

    // ws layout (bytes):
    //   T1:   [4][192][96][96] f32 = 28,311,552 @ 0
    //   WB8T: [24][24][8] f32      =     18,432 @ 28,311,552
    //   WT4:  [24][192] f32        =     18,432 @ 28,329,984
    //   S8:   [24] i32             @ 28,348,416
    //   S4:   [48] i32             @ 28,348,512
    float* T1   = (float*)(ws + 0);
    float* WB8T = (float*)(ws + 28311552);
    float* WT4  = (float*)(ws + 28329984);
    int*   S8   = (int*)(ws + 28348416);
    int*   S4   = (int*)(ws + 28348512);

    setup_kernel<<<1, N_OUT, 0, stream>>>(WB8T, WT4, S8, S4);

    // Pass 1: x-axis. in [4][96][2304 quads] -> T1 [4][192][2304 quads]
    {
        dim3 g(4 * 2304 / 256, BW, 1);  // (36, 24)
        pass_x_kernel<2304><<<g, 256, 0, stream>>>(
            (const float4*)in, (float4*)T1, WB8T, S8);
    }
    // Fused pass 2+3: T1 [768][96][96] -> out [768][192][192]
    pass_yz_kernel<<<768, 384, 0, stream>>>(T1, out, WB8T, WT4, S8, S4);
}

// Round 5
// 85.058 us; speedup vs baseline: 1.4851x; 1.4851x over previous
//
#include <hip/hip_runtime.h>
#include <math.h>

#define N_IN  96
#define N_OUT 192
#define BW    24    // truncated band window width
#define SP2   72    // LDS row stride in halfs (144B: 16B-aligned rows, 4-bank skew)

typedef _Float16 h2 __attribute__((ext_vector_type(2)));

__device__ __forceinline__ float dot2h(unsigned int w, unsigned int v, float acc) {
#if __has_builtin(__builtin_amdgcn_fdot2)
    return __builtin_amdgcn_fdot2(__builtin_bit_cast(h2, w),
                                  __builtin_bit_cast(h2, v), acc, false);
#else
    h2 a = __builtin_bit_cast(h2, w), b = __builtin_bit_cast(h2, v);
    return acc + (float)a.x * (float)b.x + (float)a.y * (float)b.y;
#endif
}

__device__ __forceinline__ unsigned int packh2(float a, float b) {
    h2 h; h.x = (_Float16)a; h.y = (_Float16)b;
    return __builtin_bit_cast(unsigned int, h);
}

__device__ __forceinline__ int fold_dct2(int idx, int n) {
    int p = 2 * n;
    int m = ((idx % p) + p) % p;
    return (m >= n) ? (p - 1 - m) : m;
}

__device__ __forceinline__ void fma4(float4& a, float w, const float4& v) {
    a.x += w * v.x; a.y += w * v.y; a.z += w * v.z; a.w += w * v.w;
}

// One-shot setup. Computes M = B_resize * A^-1 column-wise (thread j owns
// column j of M^T, i.e. row j of M restricted to its band), then emits:
//   WB8T [24 oct][24 t][8 jj] f32   : P1 weights, window start S8[oct]
//   WB4  [48 grq][24 t][4 r]  f32   : stage-A weights, same S8 windows
//   W2   [12 tp][192 j] u32(half2)  : stage-B packed tap-pairs, start S4[j/4]
__global__ void setup_kernel(float* __restrict__ WB8T, float* __restrict__ WB4,
                             unsigned int* __restrict__ W2,
                             int* __restrict__ S8, int* __restrict__ S4) {
    __shared__ float  DP[N_IN][N_OUT];  // 73.7 KB
    __shared__ double cp[N_IN];
    __shared__ double minv[N_IN];
    int j = threadIdx.x;  // 0..191

    // B row j: 4 taps at fold(b-1+k)
    double x  = (double)j * 95.0 / 191.0;
    double bf = floor(x);
    int    b  = (int)bf;
    double t  = x - bf;
    double t2 = t * t, t3 = t2 * t;
    double w[4] = {(1.0 - t) * (1.0 - t) * (1.0 - t) / 6.0,
                   (3.0 * t3 - 6.0 * t2 + 4.0) / 6.0,
                   (-3.0 * t3 + 3.0 * t2 + 3.0 * t + 1.0) / 6.0,
                   t3 / 6.0};
    int c[4];
    for (int k = 0; k < 4; ++k) c[k] = fold_dct2(b - 1 + k, N_IN);

    if (j == 0) {
        const double a = 1.0 / 6.0;
        minv[0] = 1.0 / (5.0 / 6.0);
        cp[0]   = a * minv[0];
        for (int i = 1; i < N_IN; ++i) {
            double bi  = (i == N_IN - 1) ? (5.0 / 6.0) : (2.0 / 3.0);
            double den = bi - a * cp[i - 1];
            minv[i] = 1.0 / den;
            cp[i]   = a * minv[i];
        }
    }
    __syncthreads();

    // Thomas forward on RHS = B[j,:]
    const double a = 1.0 / 6.0;
    double dp = 0.0;
    for (int i = 0; i < N_IN; ++i) {
        double Bji = 0.0;
        for (int k = 0; k < 4; ++k) if (c[k] == i) Bji += w[k];
        dp = (i == 0) ? Bji * minv[0] : (Bji - a * dp) * minv[i];
        DP[i][j] = (float)dp;
    }
    // Backward; overwrite DP[i][j] with M[j][i] (own column only -> no barrier)
    double xv = 0.0;
    for (int i = N_IN - 1; i >= 0; --i) {
        xv = (i == N_IN - 1) ? (double)DP[i][j] : ((double)DP[i][j] - cp[i] * xv);
        DP[i][j] = (float)xv;
    }

    // Window starts
    int b8 = (((j & ~7) * 95) / 191);
    int s8 = b8 - 9; s8 = s8 < 0 ? 0 : (s8 > 72 ? 72 : s8);
    int b4 = (((j & ~3) * 95) / 191);
    int s4 = (b4 - 6) & ~7; s4 = s4 < 0 ? 0 : (s4 > 72 ? 72 : s4);  // 8-aligned
    if ((j & 7) == 0) S8[j >> 3] = s8;
    if ((j & 3) == 0) S4[j >> 2] = s4;

    for (int t_ = 0; t_ < BW; ++t_) {
        float m8 = DP[s8 + t_][j];
        WB8T[((j >> 3) * BW + t_) * 8 + (j & 7)] = m8;
        WB4[((j >> 2) * BW + t_) * 4 + (j & 3)]  = m8;
    }
#pragma unroll
    for (int tp = 0; tp < 12; ++tp)
        W2[tp * N_OUT + j] = packh2(DP[s4 + 2 * tp][j], DP[s4 + 2 * tp + 1][j]);
}

// Pass 1: expand x. in f32 [4][96][9216] -> T1 fp16 [4][192][9216].
template <int QUADS>
__global__ __launch_bounds__(256)
void pass_x_kernel(const float4* __restrict__ in, uint2* __restrict__ outh,
                   const float* __restrict__ WB8T, const int* __restrict__ S8) {
    int g  = blockIdx.x * 256 + threadIdx.x;
    int o  = g / QUADS;
    int q  = g - o * QUADS;
    int jo = blockIdx.y;
    int S  = S8[jo];
    const float4* ip = in + ((size_t)o * N_IN + S) * QUADS + q;
    const float4* wp = (const float4*)(WB8T + jo * BW * 8);
    float4 acc[8];
#pragma unroll
    for (int jj = 0; jj < 8; ++jj) acc[jj] = make_float4(0.f, 0.f, 0.f, 0.f);
#pragma unroll
    for (int t = 0; t < BW; ++t) {
        float4 v   = ip[(size_t)t * QUADS];
        float4 wlo = wp[2 * t];
        float4 whi = wp[2 * t + 1];
        fma4(acc[0], wlo.x, v); fma4(acc[1], wlo.y, v);
        fma4(acc[2], wlo.z, v); fma4(acc[3], wlo.w, v);
        fma4(acc[4], whi.x, v); fma4(acc[5], whi.y, v);
        fma4(acc[6], whi.z, v); fma4(acc[7], whi.w, v);
    }
    uint2* op = outh + ((size_t)o * N_OUT + jo * 8) * QUADS + q;
#pragma unroll
    for (int jj = 0; jj < 8; ++jj) {
        uint2 pk;
        pk.x = packh2(acc[jj].x, acc[jj].y);
        pk.y = packh2(acc[jj].z, acc[jj].w);
        op[(size_t)jj * QUADS] = pk;
    }
}

// Fused pass 2+3, z'-half blocks. Block (o, zh): slab o = (bc,x'), output
// [192 y'][96 z' at zh*96]. Input cols [zbase, zbase+64) of the fp16 slab.
// Stage 0: copy -> Sl. Stage A (per y'-half): y-expand -> Ty (fp16).
// Stage B: z-expand via v_dot2_f32_f16, coalesced f32 stores.
__global__ __launch_bounds__(384)
void pass_yz_kernel(const unsigned short* __restrict__ T1h, float* __restrict__ out,
                    const float* __restrict__ WB4, const unsigned int* __restrict__ W2,
                    const int* __restrict__ S8, const int* __restrict__ S4) {
    __shared__ unsigned short Sl[N_IN * SP2];  // 13.8 KB
    __shared__ unsigned short Ty[N_IN * SP2];  // 13.8 KB
    int bid   = blockIdx.x;
    int o     = bid >> 1;
    int zh    = bid & 1;
    int zbase = zh ? 32 : 0;
    int tid   = threadIdx.x;  // 0..383

    // Stage 0: copy 96 rows x 64 halfs (8B granules, coalesced)
    {
        const unsigned short* sb = T1h + (size_t)o * N_IN * N_IN + zbase;
#pragma unroll
        for (int it = 0; it < 4; ++it) {
            int f = it * 384 + tid;        // 0..1535
            int r = f >> 4, c8 = f & 15;
            *(uint2*)(Sl + r * SP2 + c8 * 4) = *(const uint2*)(sb + r * N_IN + c8 * 4);
        }
    }

    // Stage-B constants: thread = (yg 0..7, z'-pair jp 0..47)
    int jp = tid % 48;
    int yg = tid / 48;
    int jA = zh * 96 + jp * 2;
    int c0 = S4[jA >> 2] - zbase;  // local, 8-aligned
    unsigned int wA[12], wB[12];
#pragma unroll
    for (int tp = 0; tp < 12; ++tp) {
        wA[tp] = W2[tp * N_OUT + jA];
        wB[tp] = W2[tp * N_OUT + jA + 1];
    }

    // Stage-A constants: thread = (row-quad rq 0..23, z-quad zq 0..15)
    int zq = tid & 15;
    int rq = tid >> 4;

    __syncthreads();

    for (int h = 0; h < 2; ++h) {
        // ---- Stage A: y-expand rows [h*96, h*96+96) into Ty ----
        {
            int j0  = h * 96 + rq * 4;
            int Sg  = S8[j0 >> 3];
            const float4* wp = (const float4*)(WB4 + (j0 >> 2) * BW * 4);
            const unsigned short* sp = Sl + Sg * SP2 + zq * 4;
            float4 a0 = make_float4(0.f,0.f,0.f,0.f), a1 = a0, a2 = a0, a3 = a0;
#pragma unroll
            for (int t = 0; t < BW; ++t) {
                uint2 hv = *(const uint2*)(sp + (size_t)t * SP2);
                h2 p0 = __builtin_bit_cast(h2, hv.x);
                h2 p1 = __builtin_bit_cast(h2, hv.y);
                float4 v = make_float4((float)p0.x, (float)p0.y,
                                       (float)p1.x, (float)p1.y);
                float4 wq = wp[t];
                fma4(a0, wq.x, v); fma4(a1, wq.y, v);
                fma4(a2, wq.z, v); fma4(a3, wq.w, v);
            }
            unsigned short* ty = Ty + (rq * 4) * SP2 + zq * 4;
            uint2 pk;
            pk.x = packh2(a0.x, a0.y); pk.y = packh2(a0.z, a0.w);
            *(uint2*)(ty + 0 * SP2) = pk;
            pk.x = packh2(a1.x, a1.y); pk.y = packh2(a1.z, a1.w);
            *(uint2*)(ty + 1 * SP2) = pk;
            pk.x = packh2(a2.x, a2.y); pk.y = packh2(a2.z, a2.w);
            *(uint2*)(ty + 2 * SP2) = pk;
            pk.x = packh2(a3.x, a3.y); pk.y = packh2(a3.z, a3.w);
            *(uint2*)(ty + 3 * SP2) = pk;
        }
        __syncthreads();

        // ---- Stage B: z-expand 12 rows x 2 z' per thread ----
        {
            float* ob = out + (((size_t)o * N_OUT + h * 96 + yg * 12) * N_OUT)
                        + zh * 96 + jp * 2;
#pragma unroll
            for (int rr = 0; rr < 12; ++rr) {
                const uint4* tq = (const uint4*)(Ty + (yg * 12 + rr) * SP2 + c0);
                uint4 q0 = tq[0], q1 = tq[1], q2 = tq[2];
                float sA = 0.f, sB = 0.f;
                sA = dot2h(wA[0],  q0.x, sA); sB = dot2h(wB[0],  q0.x, sB);
                sA = dot2h(wA[1],  q0.y, sA); sB = dot2h(wB[1],  q0.y, sB);
                sA = dot2h(wA[2],  q0.z, sA); sB = dot2h(wB[2],  q0.z, sB);
                sA = dot2h(wA[3],  q0.w, sA); sB = dot2h(wB[3],  q0.w, sB);
                sA = dot2h(wA[4],  q1.x, sA); sB = dot2h(wB[4],  q1.x, sB);
                sA = dot2h(wA[5],  q1.y, sA); sB = dot2h(wB[5],  q1.y, sB);
                sA = dot2h(wA[6],  q1.z, sA); sB = dot2h(wB[6],  q1.z, sB);
                sA = dot2h(wA[7],  q1.w, sA); sB = dot2h(wB[7],  q1.w, sB);
                sA = dot2h(wA[8],  q2.x, sA); sB = dot2h(wB[8],  q2.x, sB);
                sA = dot2h(wA[9],  q2.y, sA); sB = dot2h(wB[9],  q2.y, sB);
                sA = dot2h(wA[10], q2.z, sA); sB = dot2h(wB[10], q2.z, sB);
                sA = dot2h(wA[11], q2.w, sA); sB = dot2h(wB[11], q2.w, sB);
                float2 st; st.x = sA; st.y = sB;
                *(float2*)(ob + (size_t)rr * N_OUT) = st;
            }
        }
        __syncthreads();  // Ty reused by next h's stage A
    }
}

extern "C" void kernel_launch(void* const* d_in, const int* in_sizes, int n_in,
                              void* d_out, int out_size, void* d_ws, size_t ws_size,
                              hipStream_t stream) {
    const float* in  = (const float*)d_in[0];
    float*       out = (float*)d_out;
    char*        ws  = (char*)d_ws;

    // ws layout (bytes):
    //   T1h:  [4][192][9216] fp16 = 14,155,776 @ 0
    //   WB8T: [24][24][8] f32     =     18,432 @ 14,155,776
    //   WB4:  [48][24][4] f32     =     18,432 @ 14,174,208
    //   W2:   [12][192] u32       =      9,216 @ 14,192,640
    //   S8:   [24] i32            @ 14,201,856
    //   S4:   [48] i32            @ 14,201,952
    unsigned short* T1h  = (unsigned short*)(ws + 0);
    float*          WB8T = (float*)(ws + 14155776);
    float*          WB4  = (float*)(ws + 14174208);
    unsigned int*   W2   = (unsigned int*)(ws + 14192640);
    int*            S8   = (int*)(ws + 14201856);
    int*            S4   = (int*)(ws + 14201952);

    setup_kernel<<<1, N_OUT, 0, stream>>>(WB8T, WB4, W2, S8, S4);

    // Pass 1: x-axis. in [4][96][2304 f4] -> T1h [4][192][2304 h4]
    {
        dim3 g(4 * 2304 / 256, BW, 1);  // (36, 24)
        pass_x_kernel<2304><<<g, 256, 0, stream>>>(
            (const float4*)in, (uint2*)T1h, WB8T, S8);
    }
    // Fused pass 2+3: T1h [768 slabs][96][96] -> out [768][192][192]
    pass_yz_kernel<<<768 * 2, 384, 0, stream>>>(T1h, out, WB4, W2, S8, S4);
}